// Round 7
// baseline (27222.226 us; speedup 1.0000x reference)
//
#include <hip/hip_runtime.h>

#define Bsz  4
#define Lsz  4096
#define Csz  1024
#define NHsz 16
#define CSsz 16
#define HFsz 64
#define HF4sz 256
#define NCsz 256

// ---------------------------------------------------------------------------
// fp32 GEMM: C[M,N] = A[M,K] @ B[K,N].  64x64 tile, BK=16, 4x4 microtile.
// (unchanged)
// ---------------------------------------------------------------------------
__global__ __launch_bounds__(256)
void gemm64(const float* __restrict__ A, const float* __restrict__ Bm,
            float* __restrict__ Cm, int M, int N, int K)
{
  __shared__ __attribute__((aligned(16))) float As[16][68];
  __shared__ __attribute__((aligned(16))) float Bs[16][64];
  const int t  = threadIdx.x;
  const int tx = t & 15, ty = t >> 4;
  const int row0 = blockIdx.y * 64, col0 = blockIdx.x * 64;
  const int ar = t >> 2, ak = (t & 3) * 4;
  const int bk = t >> 4, bc = (t & 15) * 4;
  float acc[4][4] = {};

  for (int k0 = 0; k0 < K; k0 += 16) {
    float4 a4 = *(const float4*)&A[(size_t)(row0 + ar) * K + k0 + ak];
    float4 b4 = *(const float4*)&Bm[(size_t)(k0 + bk) * N + col0 + bc];
    As[ak + 0][ar] = a4.x; As[ak + 1][ar] = a4.y;
    As[ak + 2][ar] = a4.z; As[ak + 3][ar] = a4.w;
    *(float4*)&Bs[bk][bc] = b4;
    __syncthreads();
#pragma unroll
    for (int kk = 0; kk < 16; ++kk) {
      float4 av = *(const float4*)&As[kk][ty * 4];
      float4 bv = *(const float4*)&Bs[kk][tx * 4];
      acc[0][0] += av.x * bv.x; acc[0][1] += av.x * bv.y;
      acc[0][2] += av.x * bv.z; acc[0][3] += av.x * bv.w;
      acc[1][0] += av.y * bv.x; acc[1][1] += av.y * bv.y;
      acc[1][2] += av.y * bv.z; acc[1][3] += av.y * bv.w;
      acc[2][0] += av.z * bv.x; acc[2][1] += av.z * bv.y;
      acc[2][2] += av.z * bv.z; acc[2][3] += av.z * bv.w;
      acc[3][0] += av.w * bv.x; acc[3][1] += av.w * bv.y;
      acc[3][2] += av.w * bv.z; acc[3][3] += av.w * bv.w;
    }
    __syncthreads();
  }
#pragma unroll
  for (int r = 0; r < 4; ++r) {
    float4 v = make_float4(acc[r][0], acc[r][1], acc[r][2], acc[r][3]);
    *(float4*)&Cm[(size_t)(row0 + ty * 4 + r) * N + col0 + tx * 4] = v;
  }
}

// ---------------------------------------------------------------------------
// ilr -> coeff table (unchanged)
// ---------------------------------------------------------------------------
__global__ __launch_bounds__(256)
void ilr_coeff(const float* __restrict__ H, const float* __restrict__ Wil,
               const float* __restrict__ bil, float* __restrict__ coeff)
{
  __shared__ float sRow[4][1024];
  __shared__ float sP[4][16][17];
  const int t = threadIdx.x;
  const size_t r0 = (size_t)blockIdx.x * 4;
  for (int rr = 0; rr < 4; ++rr)
    for (int c = t; c < 1024; c += 256)
      sRow[rr][c] = H[(r0 + rr) * 1024 + c];
  __syncthreads();
  const int hh = t & 15, sl = t >> 4;
  for (int rr = 0; rr < 4; ++rr) {
    float acc = 0.f;
    for (int kk = 0; kk < 64; ++kk)
      acc += sRow[rr][sl * 64 + kk] * Wil[(sl * 64 + kk) * 16 + hh];
    sP[rr][sl][hh] = acc;
  }
  __syncthreads();
  if (t < 64) {
    const int rr = t >> 4, h2 = t & 15;
    float s = 0.f;
    for (int sl2 = 0; sl2 < 16; ++sl2) s += sP[rr][sl2][h2];
    s += bil[h2];
    const float sig = 1.f / (1.f + expf(-s));
    const int r  = (int)(r0 + rr);
    const int b  = r >> 12, l = r & 4095, nc = l >> 4, cs = l & 15;
    coeff[((b * 16 + h2) * NCsz + nc) * CSsz + cs] = sig / ((float)(cs + 1) * 64.0f);
  }
}

// ---------------------------------------------------------------------------
// pack fp32 -> (bf16 hi | bf16 lo) in one u32; unpack = exact hi+lo, rel err
// ~2^-17 (re-derived from fp32 master every chunk: no error accumulation).
// ---------------------------------------------------------------------------
__device__ __forceinline__ unsigned pack2bf(float w) {
  unsigned u  = __float_as_uint(w);
  unsigned hi = u & 0xffff0000u;
  float lo    = w - __uint_as_float(hi);
  return hi | (__float_as_uint(lo) >> 16);
}

// ---------------------------------------------------------------------------
// TTT scan v8: 1024 threads, 16 waves, per-thread live regs <= ~58 (the
// 64-VGPR cap for 1024-thr blocks is immovable -> design fits inside it).
//   A (t<512):  (n, kh) owns HALF a W1 column: W1[kh*32+k][n], 32 regs.
//               Z1/z1bp computed as k-half partials; Z1 reduced by an
//               all-thread b128 pass (P1.5); z1bp halves exchanged via sG1
//               (kh0 exports P1, kh1 combines P1.5, kh0 reads back P3).
//               W1 update: each thread updates only its 32 k (no dup work).
//   B (t>=512): w2c only: W2[qq*32+j][m], 32 regs (w2r copy REMOVED).
//               g1 reads W2 rows from sW2T: packed split-bf16 W2 in LDS,
//               col-major [m][n] with XOR swizzle (conflict-free reads),
//               repacked from the fp32 w2c master at end of P6.
// LDS ~152KB -> 1 WG/CU.  7 barriers/chunk.
// ---------------------------------------------------------------------------
__global__ __launch_bounds__(1024, 4)
void ttt_scan(const float* __restrict__ XA, const float* __restrict__ XBuf,
              const float* __restrict__ XCbuf, const float* __restrict__ coeff,
              const float* __restrict__ W1g, const float* __restrict__ W2g,
              float* __restrict__ Out)
{
  __shared__ __attribute__((aligned(16))) float sZ1 [16 * 260]; // 16.3K final Z1
  __shared__ __attribute__((aligned(16))) float sZ1b[16 * 260]; // P1: Z1 hi-partial; P5+: Z1b
  __shared__ __attribute__((aligned(16))) float sg2 [16 * 64];  // 4K
  __shared__ __attribute__((aligned(16))) float sP  [8 * 16 * 64]; // 32K Z2/Z2b partials
  __shared__ __attribute__((aligned(16))) float sG1 [16 * 256]; // 16K z1bp staging | g1
  __shared__ __attribute__((aligned(16))) unsigned sW2T[64 * 256]; // 64K packed W2
  __shared__ float sA1 [16 * 17];
  __shared__ float sA2p[2 * 16 * 17];
  __shared__ float sCoBuf[2 * 16];

  const int t   = threadIdx.x;
  const int bh  = blockIdx.x;             // 0..63
  const int b   = bh >> 4, h = bh & 15;
  const bool isA = (t < 512);
  const int n   = t & 255;                // A: W1 col ; P7 index
  const int kh  = (t >> 8) & 1;           // A: k-half ; B(P4): i-half
  const int tb  = t & 511;                // B local id
  const int m   = t & 63;                 // B: W2 col
  const int qq  = (t >> 6) & 7;           // B: 32-row slice

  float wA[32];    // A: W1 half-col | B: w2c slice
  float zz[16];    // A: Z1-acc then z1bp partial (kh1 keeps to P1.5)
  float zb8[8];    // A: its 8 z1bp finals
  float g1v[16];   // A: g1 column (P5 -> P6)
  float xa;        // all: XA element prefetch

  const float* W1h = W1g + h * HFsz * HF4sz;
  const float* W2h = W2g + h * HF4sz * HFsz;
  if (isA) {
#pragma unroll
    for (int k = 0; k < 32; ++k) wA[k] = W1h[(kh * 32 + k) * 256 + n];
  } else {
#pragma unroll
    for (int j = 0; j < 32; ++j) wA[j] = W2h[(qq * 32 + j) * 64 + m];
    // initial packed W2 copy
#pragma unroll
    for (int j = 0; j < 32; ++j) {
      const int row = qq * 32 + j;
      sW2T[m * 256 + (row ^ ((m & 7) << 3))] = pack2bf(wA[j]);
    }
  }
  {
    const int cb0 = (b * Lsz) * Csz + h * HFsz;
    if (t < 16) sCoBuf[t] = coeff[(bh * NCsz + 0) * CSsz + t];
    xa = XA[cb0 + (t >> 6) * 1024 + (t & 63)];
  }
  __syncthreads();

#pragma unroll 1
  for (int nc = 0; nc < NCsz; ++nc) {
    const int cur = nc & 1, nxt = cur ^ 1;
    const int cb  = (b * Lsz + nc * CSsz) * Csz + h * HFsz;
    const int nc1 = (nc + 1) & (NCsz - 1);
    const int cb1 = (b * Lsz + nc1 * CSsz) * Csz + h * HFsz;
    const float* __restrict__ xbG = XBuf  + cb;   // 16 rows, stride 1024
    const float* __restrict__ xcG = XCbuf + cb;

    const float cl = sCoBuf[cur * 16 + 15];
    float conext = 0.f;
    if (t < 16) conext = coeff[(bh * NCsz + nc1) * CSsz + t];

    // ---- P1: A: Z1 k-half partials -> sZ1/sZ1b, then z1bp partials
    //          (kh0 exports to sG1, kh1 keeps in zz)
    //          B(first 256): Attn1 = tril(XC@XB^T) -> sA1 ------------------
    if (isA) {
      const float* __restrict__ xb8 = xbG + kh * 32;
#pragma unroll
      for (int i = 0; i < 16; ++i) zz[i] = 0.f;
#pragma unroll
      for (int k = 0; k < 32; k += 4) {
        const float wa = wA[k], wb = wA[k + 1], wc = wA[k + 2], wd = wA[k + 3];
#pragma unroll
        for (int i = 0; i < 16; ++i) {
          const float4 x = *(const float4*)&xb8[i * 1024 + k];
          zz[i] = fmaf(x.w, wd, fmaf(x.z, wc, fmaf(x.y, wb, fmaf(x.x, wa, zz[i]))));
        }
      }
      {
        float* dst = kh ? sZ1b : sZ1;
#pragma unroll
        for (int i = 0; i < 16; ++i) dst[i * 260 + n] = zz[i];
      }
      const float* __restrict__ xc8 = xcG + kh * 32;
#pragma unroll
      for (int i = 0; i < 16; ++i) zz[i] = 0.f;
#pragma unroll
      for (int k = 0; k < 32; k += 4) {
        const float wa = wA[k], wb = wA[k + 1], wc = wA[k + 2], wd = wA[k + 3];
#pragma unroll
        for (int i = 0; i < 16; ++i) {
          const float4 x = *(const float4*)&xc8[i * 1024 + k];
          zz[i] = fmaf(x.w, wd, fmaf(x.z, wc, fmaf(x.y, wb, fmaf(x.x, wa, zz[i]))));
        }
      }
      if (!kh) {
#pragma unroll
        for (int i = 0; i < 16; ++i) sG1[i * 256 + n] = zz[i];
      }
    } else if (tb < 256) {
      const int ia = tb >> 4, ja = tb & 15;
      float a0 = 0.f, a1 = 0.f;
      if (ja <= ia) {
#pragma unroll
        for (int k = 0; k < 64; k += 8) {
          const float4 c0 = *(const float4*)&xcG[ia * 1024 + k];
          const float4 b0 = *(const float4*)&xbG[ja * 1024 + k];
          const float4 c1 = *(const float4*)&xcG[ia * 1024 + k + 4];
          const float4 b1 = *(const float4*)&xbG[ja * 1024 + k + 4];
          a0 = fmaf(c0.w, b0.w, fmaf(c0.z, b0.z, fmaf(c0.y, b0.y, fmaf(c0.x, b0.x, a0))));
          a1 = fmaf(c1.w, b1.w, fmaf(c1.z, b1.z, fmaf(c1.y, b1.y, fmaf(c1.x, b1.x, a1))));
        }
      }
      sA1[ia * 17 + ja] = a0 + a1;
    }
    __syncthreads();

    // ---- P1.5: all: sZ1 += sZ1b (Z1 reduce); A-kh1: z1bp combine --------
    {
      const int i5 = t >> 6, n5 = (t & 63) * 4;
      float4 a = *(const float4*)&sZ1 [i5 * 260 + n5];
      const float4 p = *(const float4*)&sZ1b[i5 * 260 + n5];
      a.x += p.x; a.y += p.y; a.z += p.z; a.w += p.w;
      *(float4*)&sZ1[i5 * 260 + n5] = a;
    }
    if (isA && kh) {
#pragma unroll
      for (int j = 0; j < 16; ++j) zz[j] += sG1[j * 256 + n];
#pragma unroll
      for (int j = 0; j < 8; ++j) sG1[j * 256 + n] = zz[j];  // kh0's finals
#pragma unroll
      for (int r = 0; r < 8; ++r) zb8[r] = zz[8 + r];        // keep own 8
    }
    __syncthreads();

    // ---- P2: B: Z2 partials (slice qq) -> sP ----------------------------
    if (!isA) {
      const int ko = qq << 5;
      float acc[16];
#pragma unroll
      for (int i = 0; i < 16; ++i) acc[i] = 0.f;
#pragma unroll
      for (int kk = 0; kk < 32; kk += 4) {
        const float wa = wA[kk], wb = wA[kk + 1], wc = wA[kk + 2], wd = wA[kk + 3];
#pragma unroll
        for (int i = 0; i < 16; ++i) {
          const float4 z = *(const float4*)&sZ1[i * 260 + ko + kk];
          acc[i] = fmaf(z.w, wd, fmaf(z.z, wc, fmaf(z.y, wb, fmaf(z.x, wa, acc[i]))));
        }
      }
#pragma unroll
      for (int i = 0; i < 16; ++i) sP[(qq << 10) + (i << 6) + m] = acc[i];
    }
    __syncthreads();

    // ---- P3: all: g2 = reduce(Z2) - XA -> sg2 ; coeff stage ;
    //          A-kh0 reads its z1bp finals back ---------------------------
    {
      const int i3 = t >> 6, m3 = t & 63;
      float v = 0.f;
#pragma unroll
      for (int p = 0; p < 8; ++p) v += sP[(p << 10) + (i3 << 6) + m3];
      v -= xa;
      sg2[i3 * 64 + m3] = v;
      xa = XA[cb1 + i3 * 1024 + m3];
      if (t < 16) sCoBuf[nxt * 16 + t] = conext;
    }
    if (isA && !kh) {
#pragma unroll
      for (int r = 0; r < 8; ++r) zb8[r] = sG1[r * 256 + n];
    }
    __syncthreads();

    // ---- P4: B: g1[i][n4] full-sum from packed sW2T -> sG1 --------------
    if (!isA) {
      const int n4 = tb & 255;
      const int ih = (tb >> 8) & 1;         // i-half
      float acc[8];
#pragma unroll
      for (int ii = 0; ii < 8; ++ii) acc[ii] = 0.f;
#pragma unroll
      for (int mt = 0; mt < 16; ++mt) {
        float wv[4];
#pragma unroll
        for (int d = 0; d < 4; ++d) {
          const int mm = mt * 4 + d;
          const unsigned u = sW2T[mm * 256 + (n4 ^ ((mm & 7) << 3))];
          wv[d] = __uint_as_float(u & 0xffff0000u) + __uint_as_float(u << 16);
        }
#pragma unroll
        for (int ii = 0; ii < 8; ++ii) {
          const float4 g = *(const float4*)&sg2[(ih * 8 + ii) * 64 + mt * 4];
          acc[ii] = fmaf(g.w, wv[3], fmaf(g.z, wv[2],
                    fmaf(g.y, wv[1], fmaf(g.x, wv[0], acc[ii]))));
        }
      }
#pragma unroll
      for (int ii = 0; ii < 8; ++ii) sG1[(ih * 8 + ii) * 256 + n4] = acc[ii];
    }
    __syncthreads();

    // ---- P5: A: Z1b rows [kh*8,+8) finalize -> sZ1b ---------------------
    if (isA) {
#pragma unroll
      for (int j = 0; j < 16; ++j) g1v[j] = sG1[j * 256 + n];
#pragma unroll
      for (int r = 0; r < 8; ++r) {
        const int i = kh * 8 + r;
        float at = 0.f;
#pragma unroll
        for (int j = 0; j < 16; ++j)
          if (j <= i) at = fmaf(sA1[i * 17 + j], g1v[j], at);
        sZ1b[i * 260 + n] = fmaf(-sCoBuf[cur * 16 + i], at, zb8[r]);
      }
    }
    __syncthreads();

    // ---- P6: A: Attn2 K-half -> sA2p + W1 half-update
    //          B: Z2b partials -> sP + w2c update + repack sW2T -----------
    if (isA) {
      const int ia = n >> 4, ja = n & 15;
      const int kb = kh << 7;
      float a0 = 0.f, a1 = 0.f, a2 = 0.f, a3 = 0.f;
      if (ja <= ia) {
#pragma unroll
        for (int kk = 0; kk < 128; kk += 16) {
          const float4 p0 = *(const float4*)&sZ1b[ia * 260 + kb + kk];
          const float4 z0 = *(const float4*)&sZ1 [ja * 260 + kb + kk];
          const float4 p1 = *(const float4*)&sZ1b[ia * 260 + kb + kk + 4];
          const float4 z1 = *(const float4*)&sZ1 [ja * 260 + kb + kk + 4];
          const float4 p2 = *(const float4*)&sZ1b[ia * 260 + kb + kk + 8];
          const float4 z2 = *(const float4*)&sZ1 [ja * 260 + kb + kk + 8];
          const float4 p3 = *(const float4*)&sZ1b[ia * 260 + kb + kk + 12];
          const float4 z3 = *(const float4*)&sZ1 [ja * 260 + kb + kk + 12];
          a0 = fmaf(p0.w, z0.w, fmaf(p0.z, z0.z, fmaf(p0.y, z0.y, fmaf(p0.x, z0.x, a0))));
          a1 = fmaf(p1.w, z1.w, fmaf(p1.z, z1.z, fmaf(p1.y, z1.y, fmaf(p1.x, z1.x, a1))));
          a2 = fmaf(p2.w, z2.w, fmaf(p2.z, z2.z, fmaf(p2.y, z2.y, fmaf(p2.x, z2.x, a2))));
          a3 = fmaf(p3.w, z3.w, fmaf(p3.z, z3.z, fmaf(p3.y, z3.y, fmaf(p3.x, z3.x, a3))));
        }
      }
      sA2p[kh * 272 + ia * 17 + ja] = (a0 + a1) + (a2 + a3);
      // W1 half-update: w1[k] -= cl * sum_i g1[i][n] * XB[i][kh*32+k]
#pragma unroll
      for (int j = 0; j < 16; ++j) g1v[j] *= cl;
      const float* __restrict__ xb8 = xbG + kh * 32;
#pragma unroll
      for (int i = 0; i < 16; ++i) {
#pragma unroll
        for (int k = 0; k < 32; k += 4) {
          const float4 x = *(const float4*)&xb8[i * 1024 + k];
          wA[k + 0] -= g1v[i] * x.x; wA[k + 1] -= g1v[i] * x.y;
          wA[k + 2] -= g1v[i] * x.z; wA[k + 3] -= g1v[i] * x.w;
        }
      }
    } else {
      const int ko = qq << 5;
      float acc[16];
#pragma unroll
      for (int i = 0; i < 16; ++i) acc[i] = 0.f;
#pragma unroll
      for (int kk = 0; kk < 32; kk += 4) {
        const float wa = wA[kk], wb = wA[kk + 1], wc = wA[kk + 2], wd = wA[kk + 3];
#pragma unroll
        for (int i = 0; i < 16; ++i) {
          const float4 z = *(const float4*)&sZ1b[i * 260 + ko + kk];
          acc[i] = fmaf(z.w, wd, fmaf(z.z, wc, fmaf(z.y, wb, fmaf(z.x, wa, acc[i]))));
        }
      }
#pragma unroll
      for (int i = 0; i < 16; ++i) sP[(qq << 10) + (i << 6) + m] = acc[i];
      // w2c update (pre-update Z1/g2 streams)
      float s2[16];
#pragma unroll
      for (int i = 0; i < 16; ++i) s2[i] = cl * sg2[i * 64 + m];
#pragma unroll
      for (int kk = 0; kk < 32; kk += 4) {
        float d0 = 0.f, d1 = 0.f, d2 = 0.f, d3 = 0.f;
#pragma unroll
        for (int i = 0; i < 16; ++i) {
          const float4 z = *(const float4*)&sZ1[i * 260 + ko + kk];
          d0 = fmaf(s2[i], z.x, d0); d1 = fmaf(s2[i], z.y, d1);
          d2 = fmaf(s2[i], z.z, d2); d3 = fmaf(s2[i], z.w, d3);
        }
        wA[kk + 0] -= d0; wA[kk + 1] -= d1; wA[kk + 2] -= d2; wA[kk + 3] -= d3;
      }
      // repack updated slice for next chunk's g1
#pragma unroll
      for (int j = 0; j < 32; ++j) {
        const int row = ko + j;
        sW2T[m * 256 + (row ^ ((m & 7) << 3))] = pack2bf(wA[j]);
      }
    }
    __syncthreads();

    // ---- P7: A: Z2b reduce + Attn2 combine + store (2 rows/thread).
    //      No trailing barrier: safe — next P1 writes sZ1/sZ1b/sG1/sA1,
    //      none of which P7 reads; B reaches P3 (sg2/sP writes) only after
    //      A passes the P1-end barrier, i.e. after P7 completed. ----------
    if (isA) {
      const int mm = n & 63, iq = (n >> 6) & 3;
#pragma unroll
      for (int r = 0; r < 2; ++r) {
        const int i = iq + 4 * (kh * 2 + r);
        float v = 0.f;
#pragma unroll
        for (int p = 0; p < 8; ++p) v += sP[(p << 10) + (i << 6) + mm];
        float at = 0.f;
#pragma unroll
        for (int j = 0; j < 16; ++j)
          at = fmaf(sA2p[i * 17 + j] + sA2p[272 + i * 17 + j],
                    sg2[j * 64 + mm], at);
        Out[cb + i * 1024 + mm] = v - sCoBuf[cur * 16 + i] * at;
      }
    }
  }
}

// ---------------------------------------------------------------------------
// Workspace (fp32 floats): bXC [0,16.7M) | bXB [16.7M,33.5M) | bZ2b
// [33.5M,50.3M) | bCo [50.3M,+262k).  193 MiB total.  XA (V proj) lives in
// d_out until the final GEMM overwrites it (stream-ordered, safe).
// ---------------------------------------------------------------------------
extern "C" void kernel_launch(void* const* d_in, const int* in_sizes, int n_in,
                              void* d_out, int out_size, void* d_ws, size_t ws_size,
                              hipStream_t stream)
{
  const float* H    = (const float*)d_in[0];
  const float* Wq   = (const float*)d_in[1];
  const float* Wk   = (const float*)d_in[2];
  const float* Wv   = (const float*)d_in[3];
  const float* Wo   = (const float*)d_in[4];
  const float* Wil  = (const float*)d_in[5];
  const float* bil  = (const float*)d_in[6];
  const float* W1   = (const float*)d_in[7];
  const float* W2   = (const float*)d_in[8];
  float* out        = (float*)d_out;

  float* ws    = (float*)d_ws;
  float* bXC   = ws;
  float* bXB   = ws + 16777216;
  float* bZ2b  = ws + 33554432;
  float* bCo   = ws + 50331648;
  float* bXA   = out;

  const int M = Bsz * Lsz, N = Csz, K = Csz;
  dim3 gg(N / 64, M / 64);
  dim3 bb(256);

  gemm64<<<gg, bb, 0, stream>>>(H, Wq, bXC, M, N, K);
  gemm64<<<gg, bb, 0, stream>>>(H, Wk, bXB, M, N, K);
  gemm64<<<gg, bb, 0, stream>>>(H, Wv, bXA, M, N, K);
  ilr_coeff<<<M / 4, 256, 0, stream>>>(H, Wil, bil, bCo);
  ttt_scan<<<Bsz * NHsz, 1024, 0, stream>>>(bXA, bXB, bXC, bCo, W1, W2, bZ2b);
  gemm64<<<gg, bb, 0, stream>>>(bZ2b, Wo, out, M, N, K);
}